// Round 14
// baseline (257.036 us; speedup 1.0000x reference)
//
#include <hip/hip_runtime.h>
#include <math.h>

#define BB 8
#define NN 2048
#define FF 256
#define NW 64            // packed u32 words per adjacency row
#define ALPHA 0.2f
#define L2E 1.44269504f  // log2(e)
#define BBNN (BB*NN)

typedef _Float16 f16x8 __attribute__((ext_vector_type(8)));
typedef __fp16   h16x2 __attribute__((ext_vector_type(2)));
typedef float    f32x4 __attribute__((ext_vector_type(4)));
typedef unsigned long long u64;

__device__ __forceinline__ float lrelu(float x){ return fmaxf(x, ALPHA*x); }

// ---------------------------------------------------------------- pack adj bits + x->f16 + prep W
__global__ void pack_prep(const int* __restrict__ adj, u64* __restrict__ packed,
                          const float* __restrict__ x, _Float16* __restrict__ h0,
                          const float* __restrict__ W0, const float* __restrict__ Wrest,
                          _Float16* __restrict__ Wt){
    __shared__ _Float16 Ls[64][66];
    int blk = blockIdx.x, t = threadIdx.x;
    if (blk < 64){
        int lw = blk >> 4, rest = blk & 15;
        int c0 = (rest >> 2)*64, k0 = (rest & 3)*64;
        const float* Win = (lw == 0) ? W0 : (Wrest + (size_t)(lw-1)*FF*FF);
        for (int it = 0; it < 4; ++it){
            int idx = it*256 + t;
            int r = idx >> 4, c4 = (idx & 15)*4;
            float4 v = *(const float4*)&Win[(size_t)(k0 + r)*FF + c0 + c4];
            Ls[c4+0][r] = (_Float16)v.x; Ls[c4+1][r] = (_Float16)v.y;
            Ls[c4+2][r] = (_Float16)v.z; Ls[c4+3][r] = (_Float16)v.w;
        }
        __syncthreads();
        int c = t >> 2, jch = t & 3;
        const unsigned* lp = (const unsigned*)&Ls[c][jch*16];
        int4 o0 = make_int4(lp[0], lp[1], lp[2], lp[3]);
        int4 o1 = make_int4(lp[4], lp[5], lp[6], lp[7]);
        _Float16* dst = Wt + ((size_t)lw*FF + c0 + c)*FF + k0 + jch*16;
        *(int4*)dst = o0;
        *(int4*)(dst + 8) = o1;
    }
    long long idx = (long long)blk*blockDim.x + t;
    long long stride = (long long)gridDim.x*blockDim.x;
    const long long total = (long long)BB*NN*NN;
    for (long long i = idx; i < total; i += stride){
        u64 m = __ballot(adj[i] > 0);
        if ((t & 63) == 0) packed[i >> 6] = m;
    }
    const long long nx4 = (long long)BB*NN*FF/4;
    for (long long i = idx; i < nx4; i += stride){
        float4 v = ((const float4*)x)[i];
        union { _Float16 h[4]; u64 u; } cv;
        cv.h[0] = (_Float16)v.x; cv.h[1] = (_Float16)v.y;
        cv.h[2] = (_Float16)v.z; cv.h[3] = (_Float16)v.w;
        ((u64*)h0)[i] = cv.u;
    }
}

// ---------------------------------------------------------------- Wh = h @ W -> B' fragment-major + partial f1,f2
// grid 512: blk>>1 = 64-row tile (global), blk&1 = column half (128 cols). 2 blocks/CU.
// f1p/f2p: [half][global_row] partial sums over that half's 128 cols, PRE-SCALED by log2(e).
__global__ __launch_bounds__(512,2) void gemm_hw(const _Float16* __restrict__ hin,
        const _Float16* __restrict__ Wt, const float* __restrict__ Avec,
        char* __restrict__ Bp, float* __restrict__ f1p, float* __restrict__ f2p){
    __shared__ float fred[2][64][4];
    int t = threadIdx.x, l = t & 63, wid = t >> 6;
    int wr = wid >> 2, wc = wid & 3;
    int lg = l >> 4, lr = l & 15;
    size_t i0 = (size_t)(blockIdx.x >> 1) * 64;
    int chalf = blockIdx.x & 1, c0 = chalf * 128;
    f32x4 acc[2][2] = {};
    for (int k0 = 0; k0 < FF; k0 += 32){
        f16x8 a[2], bf[2];
        #pragma unroll
        for (int m = 0; m < 2; ++m){
            int4 v = *(const int4*)&hin[(i0 + wr*32 + m*16 + lr)*FF + k0 + lg*8];
            a[m] = *(f16x8*)&v;
        }
        #pragma unroll
        for (int n = 0; n < 2; ++n){
            int4 v = *(const int4*)&Wt[(size_t)(c0 + wc*32 + n*16 + lr)*FF + k0 + lg*8];
            bf[n] = *(f16x8*)&v;
        }
        #pragma unroll
        for (int m = 0; m < 2; ++m)
            #pragma unroll
            for (int n = 0; n < 2; ++n)
                acc[m][n] = __builtin_amdgcn_mfma_f32_16x16x32_f16(a[m], bf[n], acc[m][n], 0, 0, 0);
    }
    // fragment-major B' store: chunk (c16, kb) of 1 KB; c16 = chalf*8 + wc*2 + n
    int b   = (int)(i0 >> 11);
    int i0l = (int)(i0 & (NN-1));
    char* Bpb = Bp + ((size_t)b << 20);
    int kb  = (i0l >> 5) + wr;
    #pragma unroll
    for (int m = 0; m < 2; ++m){
        int lgp = m*2 + (lg >> 1);
        int eb  = (lg & 1)*4;
        #pragma unroll
        for (int n = 0; n < 2; ++n){
            union { _Float16 h[4]; u64 u; } pk;
            pk.h[0] = (_Float16)acc[m][n][0]; pk.h[1] = (_Float16)acc[m][n][1];
            pk.h[2] = (_Float16)acc[m][n][2]; pk.h[3] = (_Float16)acc[m][n][3];
            int c16 = chalf*8 + wc*2 + n;
            size_t off = ((size_t)(c16*64 + kb) << 10) + (size_t)((lgp*16 + lr)*16 + eb*2);
            *(u64*)(Bpb + off) = pk.u;
        }
    }
    // partial f1/f2 over this half's 128 cols (fp32 from accumulators)
    float a1v[2], a2v[2];
    #pragma unroll
    for (int n = 0; n < 2; ++n){
        a1v[n] = Avec[c0 + wc*32 + n*16 + lr];
        a2v[n] = Avec[FF + c0 + wc*32 + n*16 + lr];
    }
    #pragma unroll
    for (int m = 0; m < 2; ++m){
        #pragma unroll
        for (int q = 0; q < 4; ++q){
            float p1 = 0.f, p2 = 0.f;
            #pragma unroll
            for (int n = 0; n < 2; ++n){
                float v = acc[m][n][q];
                p1 = fmaf(v, a1v[n], p1);
                p2 = fmaf(v, a2v[n], p2);
            }
            #pragma unroll
            for (int msk = 1; msk < 16; msk <<= 1){
                p1 += __shfl_xor(p1, msk);
                p2 += __shfl_xor(p2, msk);
            }
            if (lr == 0){
                fred[0][wr*32 + m*16 + lg*4 + q][wc] = p1;
                fred[1][wr*32 + m*16 + lg*4 + q][wc] = p2;
            }
        }
    }
    __syncthreads();
    if (t < 128){
        int row = t & 63, f = t >> 6;
        float v = fred[f][row][0] + fred[f][row][1] + fred[f][row][2] + fred[f][row][3];
        (f ? f2p : f1p)[chalf*BBNN + i0 + row] = v * L2E;
    }
}

// ---------------------------------------------------------------- g[b][j] = -log2( sum_i adj ? 2^(lrelu) : 0 )
__global__ __launch_bounds__(512,2) void spass_g(const u64* __restrict__ packed,
        const float* __restrict__ f1p, const float* __restrict__ f2p, float* __restrict__ g){
    __shared__ float sred[128][33];
    __shared__ float sred2[8][33];
    int blk = blockIdx.x, t = threadIdx.x;
    int b2 = blk >> 6, jt = blk & 63;
    const unsigned* pb32 = (const unsigned*)(packed + (size_t)b2*NN*(NW/2));
    const float* f1b0 = f1p + b2*NN;
    const float* f1b1 = f1p + BBNN + b2*NN;
    int jg = t & 3, ic = t >> 2;
    int j0 = jt*32 + jg*8;
    float f2v[8];
    {
        float4 a0 = *(const float4*)&f2p[b2*NN + j0];
        float4 a1 = *(const float4*)&f2p[b2*NN + j0 + 4];
        float4 b0 = *(const float4*)&f2p[BBNN + b2*NN + j0];
        float4 b1 = *(const float4*)&f2p[BBNN + b2*NN + j0 + 4];
        f2v[0]=a0.x+b0.x; f2v[1]=a0.y+b0.y; f2v[2]=a0.z+b0.z; f2v[3]=a0.w+b0.w;
        f2v[4]=a1.x+b1.x; f2v[5]=a1.y+b1.y; f2v[6]=a1.z+b1.z; f2v[7]=a1.w+b1.w;
    }
    int wi = jt, sh = jg*8;
    float acc[8] = {};
    #pragma unroll 4
    for (int ii = 0; ii < 16; ++ii){
        int i = ic*16 + ii;
        unsigned w = pb32[(size_t)i*NW + wi] >> sh;
        float f1v = f1b0[i] + f1b1[i];
        #pragma unroll
        for (int e = 0; e < 8; ++e){
            float xv = f1v + f2v[e];
            float p = __builtin_amdgcn_exp2f(fmaxf(xv, ALPHA*xv));
            acc[e] += ((w >> e) & 1u) ? p : 0.f;
        }
    }
    #pragma unroll
    for (int e = 0; e < 8; ++e) sred[ic][jg*8 + e] = acc[e];
    __syncthreads();
    if (t < 256){
        int j = t & 31, part = t >> 5;
        float s = 0.f;
        #pragma unroll
        for (int k = 0; k < 16; ++k) s += sred[part*16 + k][j];
        sred2[part][j] = s;
    }
    __syncthreads();
    if (t < 32){
        float s = 0.f;
        #pragma unroll
        for (int p = 0; p < 8; ++p) s += sred2[p][t];
        g[b2*NN + jt*32 + t] = -__builtin_amdgcn_logf(s);
    }
}

// ---------------------------------------------------------------- hout = lrelu( P' @ Wh ): 128-j pipeline steps
// tile 64 rows x 256 cols; 8 waves, wave tile 64x32; grid 256: b = blk&7.
// Ps[2] 16 KB each (64 rows x 128 j), FG 16 KB; 16 steps, 16 barriers.
__global__ __launch_bounds__(512,2) void gemm_att(const char* __restrict__ Bp,
        const u64* __restrict__ packed64, const float* __restrict__ f1p,
        const float* __restrict__ f2p, const float* __restrict__ g,
        _Float16* __restrict__ hnext, float* __restrict__ out, int last){
    __shared__ char Ps0[16384];
    __shared__ char Ps1[16384];
    __shared__ float FG[2][NN];
    int t = threadIdx.x, l = t & 63, wid = t >> 6;
    int lg = l >> 4, lr = l & 15;
    int b  = blockIdx.x & 7;
    int i0 = (blockIdx.x >> 3) * 64;
    const char* Bpw = Bp + ((size_t)b << 20) + ((size_t)(wid*2*64) << 10) + (size_t)(l << 4);
    const u64* pb = packed64 + (size_t)b*NN*(NW/2);
    // stage f2 (sum of halves) and g into LDS
    {
        float4 a = ((const float4*)(f2p + b*NN))[t];
        float4 c = ((const float4*)(f2p + BBNN + b*NN))[t];
        float4 s; s.x=a.x+c.x; s.y=a.y+c.y; s.z=a.z+c.z; s.w=a.w+c.w;
        ((float4*)&FG[0][0])[t] = s;
        ((float4*)&FG[1][0])[t] = ((const float4*)(g + b*NN))[t];
    }
    // P-gen: thread owns row = t>>3, two 8-j chunks at (t&7)*8 and 64+(t&7)*8 of the 64x128 tile
    int prow = t >> 3, pch = t & 7;
    int grow = b*NN + i0 + prow;
    float f1v = f1p[grow] + f1p[BBNN + grow];
    const u64* prowp = pb + (size_t)(i0 + prow)*(NW/2);
    int psrow = prow*256;
    int swz = (prow & 7) << 4;
    int psoA = psrow + ((pch << 4) ^ swz);
    int psoB = psrow + (((8 + pch) << 4) ^ swz);

    int4 brega[8], bregb[8];
    float fva[8], gva[8], fvb[8], gvb[8];
    unsigned w8a, w8b;
    f32x4 acc[4][2] = {};

    #define LOADB(reg_, KS_) do{                                                       \
        _Pragma("unroll")                                                              \
        for (int n = 0; n < 2; ++n)                                                    \
          _Pragma("unroll")                                                            \
          for (int kk = 0; kk < 4; ++kk)                                               \
            reg_[n*4+kk] = *(const int4*)(Bpw + (((size_t)(n*64 + (KS_)*4 + kk)) << 10)); \
    }while(0)

    #define LOADP(KS_) do{                                                             \
        w8a = (unsigned)(prowp[(KS_)*2]   >> (pch*8)) & 0xffu;                         \
        w8b = (unsigned)(prowp[(KS_)*2+1] >> (pch*8)) & 0xffu;                         \
        int ja_ = (KS_)*128 + pch*8;                                                   \
        int jb_ = ja_ + 64;                                                            \
        *(float4*)&fva[0] = *(const float4*)&FG[0][ja_];                               \
        *(float4*)&fva[4] = *(const float4*)&FG[0][ja_+4];                             \
        *(float4*)&gva[0] = *(const float4*)&FG[1][ja_];                               \
        *(float4*)&gva[4] = *(const float4*)&FG[1][ja_+4];                             \
        *(float4*)&fvb[0] = *(const float4*)&FG[0][jb_];                               \
        *(float4*)&fvb[4] = *(const float4*)&FG[0][jb_+4];                             \
        *(float4*)&gvb[0] = *(const float4*)&FG[1][jb_];                               \
        *(float4*)&gvb[4] = *(const float4*)&FG[1][jb_+4];                             \
    }while(0)

    #define WRITEP(pbase_) do{                                                         \
        float pfa_[8], pfb_[8];                                                        \
        _Pragma("unroll")                                                              \
        for (int e = 0; e < 8; ++e){                                                   \
            float xa_ = f1v + fva[e];                                                  \
            float pa2_ = __builtin_amdgcn_exp2f(fmaxf(xa_, ALPHA*xa_) + gva[e]);       \
            pfa_[e] = ((w8a >> e) & 1u) ? pa2_ : 0.f;                                  \
            float xb_ = f1v + fvb[e];                                                  \
            float pb2_ = __builtin_amdgcn_exp2f(fmaxf(xb_, ALPHA*xb_) + gvb[e]);       \
            pfb_[e] = ((w8b >> e) & 1u) ? pb2_ : 0.f;                                  \
        }                                                                              \
        union { h16x2 h2[4]; f16x8 v8; } ua_, ub_;                                     \
        ua_.h2[0] = __builtin_amdgcn_cvt_pkrtz(pfa_[0], pfa_[1]);                      \
        ua_.h2[1] = __builtin_amdgcn_cvt_pkrtz(pfa_[2], pfa_[3]);                      \
        ua_.h2[2] = __builtin_amdgcn_cvt_pkrtz(pfa_[4], pfa_[5]);                      \
        ua_.h2[3] = __builtin_amdgcn_cvt_pkrtz(pfa_[6], pfa_[7]);                      \
        ub_.h2[0] = __builtin_amdgcn_cvt_pkrtz(pfb_[0], pfb_[1]);                      \
        ub_.h2[1] = __builtin_amdgcn_cvt_pkrtz(pfb_[2], pfb_[3]);                      \
        ub_.h2[2] = __builtin_amdgcn_cvt_pkrtz(pfb_[4], pfb_[5]);                      \
        ub_.h2[3] = __builtin_amdgcn_cvt_pkrtz(pfb_[6], pfb_[7]);                      \
        *(f16x8*)((pbase_) + psoA) = ua_.v8;                                           \
        *(f16x8*)((pbase_) + psoB) = ub_.v8;                                           \
    }while(0)

    // A-frag chunk index = h*8 + kk*4 + lg  (h = 64-j half, kk = 32-k chunk)
    #define MFMA_STEP(reg_, pbase_) do{                                                \
        _Pragma("unroll")                                                              \
        for (int h = 0; h < 2; ++h)                                                    \
          _Pragma("unroll")                                                            \
          for (int kk = 0; kk < 2; ++kk){                                              \
            f16x8 pa_[4];                                                              \
            _Pragma("unroll")                                                          \
            for (int m = 0; m < 4; ++m){                                               \
                int row_ = m*16 + lr;                                                  \
                pa_[m] = *(const f16x8*)((pbase_) + row_*256 + ((((h*8 + kk*4 + lg)) << 4) ^ ((row_ & 7) << 4))); \
            }                                                                          \
            _Pragma("unroll")                                                          \
            for (int n = 0; n < 2; ++n){                                               \
                f16x8 bf_ = *(const f16x8*)&reg_[n*4 + h*2 + kk];                      \
                _Pragma("unroll")                                                      \
                for (int m = 0; m < 4; ++m)                                            \
                    acc[m][n] = __builtin_amdgcn_mfma_f32_16x16x32_f16(pa_[m], bf_, acc[m][n], 0, 0, 0); \
            }                                                                          \
          }                                                                            \
    }while(0)

    LOADB(brega, 0);
    __syncthreads();                 // FG staged
    LOADP(0); WRITEP(Ps0);
    __syncthreads();
    for (int ks2 = 0; ks2 < 8; ++ks2){
        int s = 2*ks2;
        LOADB(bregb, s+1); LOADP(s+1);
        MFMA_STEP(brega, Ps0);
        WRITEP(Ps1);
        __syncthreads();
        if (ks2 < 7){ LOADB(brega, s+2); LOADP(s+2); }
        MFMA_STEP(bregb, Ps1);
        if (ks2 < 7){ WRITEP(Ps0); __syncthreads(); }
    }
    #undef LOADB
    #undef LOADP
    #undef WRITEP
    #undef MFMA_STEP

    size_t obase = (size_t)b*NN*FF;
    #pragma unroll
    for (int m = 0; m < 4; ++m){
        #pragma unroll
        for (int q = 0; q < 4; ++q){
            size_t row = i0 + m*16 + lg*4 + q;
            #pragma unroll
            for (int n = 0; n < 2; ++n){
                int col = wid*32 + n*16 + lr;
                float v = lrelu(acc[m][n][q]);
                if (last) out[obase + row*FF + col] = v;
                else      hnext[obase + row*FF + col] = (_Float16)v;
            }
        }
    }
}

// ----------------------------------------------------------------
extern "C" void kernel_launch(void* const* d_in, const int* in_sizes, int n_in,
                              void* d_out, int out_size, void* d_ws, size_t ws_size,
                              hipStream_t stream){
    const float* x     = (const float*)d_in[0];
    const int*   adj   = (const int*)  d_in[1];
    const float* W0    = (const float*)d_in[2];
    const float* Wrest = (const float*)d_in[3];
    const float* A     = (const float*)d_in[4];
    float* out = (float*)d_out;

    char* ws = (char*)d_ws;
    size_t off = 0;
    auto carve = [&](size_t bytes) -> void* {
        void* p = ws + off;
        off += (bytes + 255) & ~(size_t)255;
        return p;
    };
    u64*      packed = (u64*)     carve((size_t)BB*NN*NN/8);
    _Float16* hA     = (_Float16*)carve((size_t)BB*NN*FF*2);
    _Float16* hB     = (_Float16*)carve((size_t)BB*NN*FF*2);
    char*     Bp     = (char*)    carve((size_t)BB*NN*FF*2);   // fragment-major Wh panels
    _Float16* Wt     = (_Float16*)carve((size_t)4*FF*FF*2);
    float*    f1p    = (float*)   carve((size_t)2*BBNN*4);     // [half][global row]
    float*    f2p    = (float*)   carve((size_t)2*BBNN*4);
    float*    g      = (float*)   carve((size_t)BBNN*4);

    pack_prep<<<2048, 256, 0, stream>>>(adj, packed, x, hA, W0, Wrest, Wt);

    _Float16* bufs[2] = {hA, hB};
    const _Float16* hin = hA;
    for (int layer = 0; layer < 4; ++layer){
        const float* Al = A + (size_t)layer*2*FF;
        gemm_hw<<<512, 512, 0, stream>>>(hin, Wt + (size_t)layer*FF*FF, Al, Bp, f1p, f2p);
        spass_g<<<512, 512, 0, stream>>>(packed, f1p, f2p, g);
        int last = (layer == 3);
        _Float16* hnext = bufs[(layer + 1) & 1];
        gemm_att<<<256, 512, 0, stream>>>(Bp, packed, f1p, f2p, g, hnext, out, last);
        hin = hnext;
    }
}

// Round 15
// 212.266 us; speedup vs baseline: 1.2109x; 1.2109x over previous
//
#include <hip/hip_runtime.h>
#include <math.h>

#define BB 8
#define NN 2048
#define FF 256
#define NW 64            // packed u32 words per adjacency row
#define ALPHA 0.2f
#define L2E 1.44269504f  // log2(e)
#define BBNN (BB*NN)

typedef _Float16 f16x8 __attribute__((ext_vector_type(8)));
typedef __fp16   h16x2 __attribute__((ext_vector_type(2)));
typedef float    f32x4 __attribute__((ext_vector_type(4)));
typedef unsigned long long u64;

__device__ __forceinline__ float lrelu(float x){ return fmaxf(x, ALPHA*x); }

// ---------------------------------------------------------------- pack adj bits + x->f16 + prep W
__global__ void pack_prep(const int* __restrict__ adj, u64* __restrict__ packed,
                          const float* __restrict__ x, _Float16* __restrict__ h0,
                          const float* __restrict__ W0, const float* __restrict__ Wrest,
                          _Float16* __restrict__ Wt){
    __shared__ _Float16 Ls[64][66];
    int blk = blockIdx.x, t = threadIdx.x;
    if (blk < 64){
        int lw = blk >> 4, rest = blk & 15;
        int c0 = (rest >> 2)*64, k0 = (rest & 3)*64;
        const float* Win = (lw == 0) ? W0 : (Wrest + (size_t)(lw-1)*FF*FF);
        for (int it = 0; it < 4; ++it){
            int idx = it*256 + t;
            int r = idx >> 4, c4 = (idx & 15)*4;
            float4 v = *(const float4*)&Win[(size_t)(k0 + r)*FF + c0 + c4];
            Ls[c4+0][r] = (_Float16)v.x; Ls[c4+1][r] = (_Float16)v.y;
            Ls[c4+2][r] = (_Float16)v.z; Ls[c4+3][r] = (_Float16)v.w;
        }
        __syncthreads();
        int c = t >> 2, jch = t & 3;
        const unsigned* lp = (const unsigned*)&Ls[c][jch*16];
        int4 o0 = make_int4(lp[0], lp[1], lp[2], lp[3]);
        int4 o1 = make_int4(lp[4], lp[5], lp[6], lp[7]);
        _Float16* dst = Wt + ((size_t)lw*FF + c0 + c)*FF + k0 + jch*16;
        *(int4*)dst = o0;
        *(int4*)(dst + 8) = o1;
    }
    long long idx = (long long)blk*blockDim.x + t;
    long long stride = (long long)gridDim.x*blockDim.x;
    const long long total = (long long)BB*NN*NN;
    for (long long i = idx; i < total; i += stride){
        u64 m = __ballot(adj[i] > 0);
        if ((t & 63) == 0) packed[i >> 6] = m;
    }
    const long long nx4 = (long long)BB*NN*FF/4;
    for (long long i = idx; i < nx4; i += stride){
        float4 v = ((const float4*)x)[i];
        union { _Float16 h[4]; u64 u; } cv;
        cv.h[0] = (_Float16)v.x; cv.h[1] = (_Float16)v.y;
        cv.h[2] = (_Float16)v.z; cv.h[3] = (_Float16)v.w;
        ((u64*)h0)[i] = cv.u;
    }
}

// ---------------------------------------------------------------- layer-0 hw: Wh = h @ W -> B' fragment-major + f1,f2 (x L2E)
__global__ __launch_bounds__(512,2) void gemm_hw(const _Float16* __restrict__ hin,
        const _Float16* __restrict__ Wt, const float* __restrict__ Avec,
        char* __restrict__ Bp, float* __restrict__ f1, float* __restrict__ f2){
    __shared__ float fred[2][64][4];
    int t = threadIdx.x, l = t & 63, wid = t >> 6;
    int wr = wid >> 2, wc = wid & 3;
    int lg = l >> 4, lr = l & 15;
    size_t i0 = (size_t)blockIdx.x * 64;
    f32x4 acc[2][4] = {};
    for (int k0 = 0; k0 < FF; k0 += 32){
        f16x8 a[2], bf[4];
        #pragma unroll
        for (int m = 0; m < 2; ++m){
            int4 v = *(const int4*)&hin[(i0 + wr*32 + m*16 + lr)*FF + k0 + lg*8];
            a[m] = *(f16x8*)&v;
        }
        #pragma unroll
        for (int n = 0; n < 4; ++n){
            int4 v = *(const int4*)&Wt[(size_t)(wc*64 + n*16 + lr)*FF + k0 + lg*8];
            bf[n] = *(f16x8*)&v;
        }
        #pragma unroll
        for (int m = 0; m < 2; ++m)
            #pragma unroll
            for (int n = 0; n < 4; ++n)
                acc[m][n] = __builtin_amdgcn_mfma_f32_16x16x32_f16(a[m], bf[n], acc[m][n], 0, 0, 0);
    }
    int b   = (int)(i0 >> 11);
    int i0l = (int)(i0 & (NN-1));
    char* Bpb = Bp + ((size_t)b << 20);
    int kb  = (i0l >> 5) + wr;
    #pragma unroll
    for (int m = 0; m < 2; ++m){
        int lgp = m*2 + (lg >> 1);
        int eb  = (lg & 1)*4;
        #pragma unroll
        for (int n = 0; n < 4; ++n){
            union { _Float16 h[4]; u64 u; } pk;
            pk.h[0] = (_Float16)acc[m][n][0]; pk.h[1] = (_Float16)acc[m][n][1];
            pk.h[2] = (_Float16)acc[m][n][2]; pk.h[3] = (_Float16)acc[m][n][3];
            int c16 = wc*4 + n;
            size_t off = ((size_t)(c16*64 + kb) << 10) + (size_t)((lgp*16 + lr)*16 + eb*2);
            *(u64*)(Bpb + off) = pk.u;
        }
    }
    float a1v[4], a2v[4];
    #pragma unroll
    for (int n = 0; n < 4; ++n){
        a1v[n] = Avec[wc*64 + n*16 + lr];
        a2v[n] = Avec[FF + wc*64 + n*16 + lr];
    }
    #pragma unroll
    for (int m = 0; m < 2; ++m){
        #pragma unroll
        for (int q = 0; q < 4; ++q){
            float p1 = 0.f, p2 = 0.f;
            #pragma unroll
            for (int n = 0; n < 4; ++n){
                float v = acc[m][n][q];
                p1 = fmaf(v, a1v[n], p1);
                p2 = fmaf(v, a2v[n], p2);
            }
            #pragma unroll
            for (int msk = 1; msk < 16; msk <<= 1){
                p1 += __shfl_xor(p1, msk);
                p2 += __shfl_xor(p2, msk);
            }
            if (lr == 0){
                fred[0][wr*32 + m*16 + lg*4 + q][wc] = p1;
                fred[1][wr*32 + m*16 + lg*4 + q][wc] = p2;
            }
        }
    }
    __syncthreads();
    if (t < 128){
        int row = t & 63, f = t >> 6;
        float v = fred[f][row][0] + fred[f][row][1] + fred[f][row][2] + fred[f][row][3];
        (f ? f2 : f1)[i0 + row] = v * L2E;
    }
}

// ---------------------------------------------------------------- g[b][j] = -log2( sum_i adj ? 2^(lrelu) : 0 )
__global__ __launch_bounds__(512,2) void spass_g(const u64* __restrict__ packed,
        const float* __restrict__ f1, const float* __restrict__ f2, float* __restrict__ g){
    __shared__ float sred[128][33];
    __shared__ float sred2[8][33];
    int blk = blockIdx.x, t = threadIdx.x;
    int b2 = blk >> 6, jt = blk & 63;
    const unsigned* pb32 = (const unsigned*)(packed + (size_t)b2*NN*(NW/2));
    const float* f1b = f1 + b2*NN;
    int jg = t & 3, ic = t >> 2;
    int j0 = jt*32 + jg*8;
    float f2v[8];
    *(float4*)&f2v[0] = *(const float4*)&f2[b2*NN + j0];
    *(float4*)&f2v[4] = *(const float4*)&f2[b2*NN + j0 + 4];
    int wi = jt, sh = jg*8;
    float acc[8] = {};
    #pragma unroll 4
    for (int ii = 0; ii < 16; ++ii){
        int i = ic*16 + ii;
        unsigned w = pb32[(size_t)i*NW + wi] >> sh;
        float f1v = f1b[i];
        #pragma unroll
        for (int e = 0; e < 8; ++e){
            float xv = f1v + f2v[e];
            float p = __builtin_amdgcn_exp2f(fmaxf(xv, ALPHA*xv));
            acc[e] += ((w >> e) & 1u) ? p : 0.f;
        }
    }
    #pragma unroll
    for (int e = 0; e < 8; ++e) sred[ic][jg*8 + e] = acc[e];
    __syncthreads();
    if (t < 256){
        int j = t & 31, part = t >> 5;
        float s = 0.f;
        #pragma unroll
        for (int k = 0; k < 16; ++k) s += sred[part*16 + k][j];
        sred2[part][j] = s;
    }
    __syncthreads();
    if (t < 32){
        float s = 0.f;
        #pragma unroll
        for (int p = 0; p < 8; ++p) s += sred2[p][t];
        g[b2*NN + jt*32 + t] = -__builtin_amdgcn_logf(s);
    }
}

// ---------------------------------------------------------------- fused: att(l) -> H in LDS -> hw(l+1)
// grid 256: b = blk&7, i0 = (blk>>3)*64 (strip-local). Phase 1 = round-13 att; phase 2 = round-13 hw from LDS.
__global__ __launch_bounds__(512,2) void att_hw(const char* __restrict__ Bp_in,
        char* __restrict__ Bp_out, const u64* __restrict__ packed64,
        const float* __restrict__ f1_in, const float* __restrict__ f2_in,
        const float* __restrict__ g, const _Float16* __restrict__ Wt,
        const float* __restrict__ Avec, float* __restrict__ f1_out, float* __restrict__ f2_out){
    __shared__ __align__(16) char SM[34816];   // [0,8K)=Ps0 [8K,16K)=Ps1 [16K,32K)=FG | phase2: [0,32K)=Hs [32K,34K)=fred
    char* Ps0 = SM;
    char* Ps1 = SM + 8192;
    float* FG0 = (float*)(SM + 16384);         // f2s
    float* FG1 = FG0 + NN;                     // g
    int t = threadIdx.x, l = t & 63, wid = t >> 6;
    int lg = l >> 4, lr = l & 15;
    int b  = blockIdx.x & 7;
    int i0 = (blockIdx.x >> 3) * 64;           // strip-local row base (0..2047-63)
    const char* Bpw = Bp_in + ((size_t)b << 20) + ((size_t)(wid*2*64) << 10) + (size_t)(l << 4);
    const u64* pb = packed64 + (size_t)b*NN*(NW/2);
    ((float4*)FG0)[t] = ((const float4*)(f2_in + b*NN))[t];
    ((float4*)FG1)[t] = ((const float4*)(g + b*NN))[t];
    int prow = t >> 3, pch = t & 7;
    float f1v = f1_in[b*NN + i0 + prow];
    const u64* prowp = pb + (size_t)(i0 + prow)*(NW/2);
    int pso = prow*128 + ((pch << 4) ^ ((prow & 7) << 4));

    int4 brega[4], bregb[4];
    float fv[8], gv[8];
    unsigned w8;
    f32x4 acc[4][2] = {};

    #define LOADB(reg_, ks_) do{                                                       \
        _Pragma("unroll")                                                              \
        for (int n = 0; n < 2; ++n)                                                    \
          _Pragma("unroll")                                                            \
          for (int kk = 0; kk < 2; ++kk)                                               \
            reg_[n*2+kk] = *(const int4*)(Bpw + (((size_t)(n*64 + (ks_)*2 + kk)) << 10)); \
    }while(0)

    #define LOADP(ks_) do{                                                             \
        w8 = (unsigned)(prowp[ks_] >> (pch*8)) & 0xffu;                                \
        int jb_ = (ks_)*64 + pch*8;                                                    \
        *(float4*)&fv[0] = *(const float4*)&FG0[jb_];                                  \
        *(float4*)&fv[4] = *(const float4*)&FG0[jb_+4];                                \
        *(float4*)&gv[0] = *(const float4*)&FG1[jb_];                                  \
        *(float4*)&gv[4] = *(const float4*)&FG1[jb_+4];                                \
    }while(0)

    #define WRITEP(pbase_) do{                                                         \
        float pf_[8];                                                                  \
        _Pragma("unroll")                                                              \
        for (int e = 0; e < 8; ++e){                                                   \
            float xv_ = f1v + fv[e];                                                   \
            float p_ = __builtin_amdgcn_exp2f(fmaxf(xv_, ALPHA*xv_) + gv[e]);          \
            pf_[e] = ((w8 >> e) & 1u) ? p_ : 0.f;                                      \
        }                                                                              \
        union { h16x2 h2[4]; f16x8 v8; } pu_;                                          \
        pu_.h2[0] = __builtin_amdgcn_cvt_pkrtz(pf_[0], pf_[1]);                        \
        pu_.h2[1] = __builtin_amdgcn_cvt_pkrtz(pf_[2], pf_[3]);                        \
        pu_.h2[2] = __builtin_amdgcn_cvt_pkrtz(pf_[4], pf_[5]);                        \
        pu_.h2[3] = __builtin_amdgcn_cvt_pkrtz(pf_[6], pf_[7]);                        \
        *(f16x8*)((pbase_) + pso) = pu_.v8;                                            \
    }while(0)

    #define MFMA_STEP(reg_, pbase_) do{                                                \
        f16x8 pa_[4][2];                                                               \
        _Pragma("unroll")                                                              \
        for (int m = 0; m < 4; ++m){                                                   \
            int row_ = m*16 + lr;                                                      \
            _Pragma("unroll")                                                          \
            for (int kk = 0; kk < 2; ++kk)                                             \
                pa_[m][kk] = *(const f16x8*)((pbase_) + row_*128 + (((kk*4 + lg) << 4) ^ ((row_ & 7) << 4))); \
        }                                                                              \
        _Pragma("unroll")                                                              \
        for (int n = 0; n < 2; ++n)                                                    \
          _Pragma("unroll")                                                            \
          for (int kk = 0; kk < 2; ++kk){                                              \
            f16x8 bf_ = *(const f16x8*)&reg_[n*2+kk];                                  \
            _Pragma("unroll")                                                          \
            for (int m = 0; m < 4; ++m)                                                \
                acc[m][n] = __builtin_amdgcn_mfma_f32_16x16x32_f16(pa_[m][kk], bf_, acc[m][n], 0, 0, 0); \
          }                                                                            \
    }while(0)

    LOADB(brega, 0);
    __syncthreads();
    LOADP(0); WRITEP(Ps0);
    __syncthreads();
    for (int ks2 = 0; ks2 < 16; ++ks2){
        int s = 2*ks2;
        LOADB(bregb, s+1); LOADP(s+1);
        MFMA_STEP(brega, Ps0);
        WRITEP(Ps1);
        __syncthreads();
        if (ks2 < 15){ LOADB(brega, s+2); LOADP(s+2); }
        MFMA_STEP(bregb, Ps1);
        if (ks2 < 15){ WRITEP(Ps0); __syncthreads(); }
    }
    #undef LOADB
    #undef LOADP
    #undef WRITEP
    #undef MFMA_STEP

    // ---- handoff: H = lrelu(att) -> swizzled LDS f16 tile (aliases Ps/FG region)
    __syncthreads();    // all waves done reading Ps/FG
    #pragma unroll
    for (int m = 0; m < 4; ++m){
        #pragma unroll
        for (int q = 0; q < 4; ++q){
            int row = m*16 + lg*4 + q;
            #pragma unroll
            for (int n = 0; n < 2; ++n){
                int col = wid*32 + n*16 + lr;
                float v = lrelu(acc[m][n][q]);
                *(_Float16*)(SM + row*512 + ((col*2) ^ ((row & 7) << 4))) = (_Float16)v;
            }
        }
    }
    __syncthreads();    // Hs visible

    // ---- phase 2: hw for next layer (round-13 body, A from Hs)
    {
        float (*fred)[64][4] = (float(*)[64][4])(SM + 32768);
        int wr = wid >> 2, wc = wid & 3;
        f32x4 acc2[2][4] = {};
        for (int k0 = 0; k0 < FF; k0 += 32){
            f16x8 a[2], bf[4];
            #pragma unroll
            for (int m = 0; m < 2; ++m){
                int row = wr*32 + m*16 + lr;
                a[m] = *(const f16x8*)(SM + row*512 + (((k0 + lg*8)*2) ^ ((row & 7) << 4)));
            }
            #pragma unroll
            for (int n = 0; n < 4; ++n){
                int4 v = *(const int4*)&Wt[(size_t)(wc*64 + n*16 + lr)*FF + k0 + lg*8];
                bf[n] = *(f16x8*)&v;
            }
            #pragma unroll
            for (int m = 0; m < 2; ++m)
                #pragma unroll
                for (int n = 0; n < 4; ++n)
                    acc2[m][n] = __builtin_amdgcn_mfma_f32_16x16x32_f16(a[m], bf[n], acc2[m][n], 0, 0, 0);
        }
        char* Bpb = Bp_out + ((size_t)b << 20);
        int kb = (i0 >> 5) + wr;
        #pragma unroll
        for (int m = 0; m < 2; ++m){
            int lgp = m*2 + (lg >> 1);
            int eb  = (lg & 1)*4;
            #pragma unroll
            for (int n = 0; n < 4; ++n){
                union { _Float16 h[4]; u64 u; } pk;
                pk.h[0] = (_Float16)acc2[m][n][0]; pk.h[1] = (_Float16)acc2[m][n][1];
                pk.h[2] = (_Float16)acc2[m][n][2]; pk.h[3] = (_Float16)acc2[m][n][3];
                int c16 = wc*4 + n;
                size_t off = ((size_t)(c16*64 + kb) << 10) + (size_t)((lgp*16 + lr)*16 + eb*2);
                *(u64*)(Bpb + off) = pk.u;
            }
        }
        float a1v[4], a2v[4];
        #pragma unroll
        for (int n = 0; n < 4; ++n){
            a1v[n] = Avec[wc*64 + n*16 + lr];
            a2v[n] = Avec[FF + wc*64 + n*16 + lr];
        }
        #pragma unroll
        for (int m = 0; m < 2; ++m){
            #pragma unroll
            for (int q = 0; q < 4; ++q){
                float p1 = 0.f, p2 = 0.f;
                #pragma unroll
                for (int n = 0; n < 4; ++n){
                    float v = acc2[m][n][q];
                    p1 = fmaf(v, a1v[n], p1);
                    p2 = fmaf(v, a2v[n], p2);
                }
                #pragma unroll
                for (int msk = 1; msk < 16; msk <<= 1){
                    p1 += __shfl_xor(p1, msk);
                    p2 += __shfl_xor(p2, msk);
                }
                if (lr == 0){
                    fred[0][wr*32 + m*16 + lg*4 + q][wc] = p1;
                    fred[1][wr*32 + m*16 + lg*4 + q][wc] = p2;
                }
            }
        }
        __syncthreads();
        if (t < 128){
            int row = t & 63, f = t >> 6;
            float v = fred[f][row][0] + fred[f][row][1] + fred[f][row][2] + fred[f][row][3];
            (f ? f2_out : f1_out)[b*NN + i0 + row] = v * L2E;
        }
    }
}

// ---------------------------------------------------------------- final att: out = lrelu( P' @ Wh ) (f32)
__global__ __launch_bounds__(512,2) void att_last(const char* __restrict__ Bp,
        const u64* __restrict__ packed64, const float* __restrict__ f1,
        const float* __restrict__ f2, const float* __restrict__ g, float* __restrict__ out){
    __shared__ char Ps0[8192];
    __shared__ char Ps1[8192];
    __shared__ float FG[2][NN];
    int t = threadIdx.x, l = t & 63, wid = t >> 6;
    int lg = l >> 4, lr = l & 15;
    int b  = blockIdx.x & 7;
    int i0 = (blockIdx.x >> 3) * 64;
    const char* Bpw = Bp + ((size_t)b << 20) + ((size_t)(wid*2*64) << 10) + (size_t)(l << 4);
    const u64* pb = packed64 + (size_t)b*NN*(NW/2);
    ((float4*)&FG[0][0])[t] = ((const float4*)(f2 + b*NN))[t];
    ((float4*)&FG[1][0])[t] = ((const float4*)(g  + b*NN))[t];
    int prow = t >> 3, pch = t & 7;
    float f1v = f1[b*NN + i0 + prow];
    const u64* prowp = pb + (size_t)(i0 + prow)*(NW/2);
    int pso = prow*128 + ((pch << 4) ^ ((prow & 7) << 4));

    int4 brega[4], bregb[4];
    float fv[8], gv[8];
    unsigned w8;
    f32x4 acc[4][2] = {};

    #define LOADB(reg_, ks_) do{                                                       \
        _Pragma("unroll")                                                              \
        for (int n = 0; n < 2; ++n)                                                    \
          _Pragma("unroll")                                                            \
          for (int kk = 0; kk < 2; ++kk)                                               \
            reg_[n*2+kk] = *(const int4*)(Bpw + (((size_t)(n*64 + (ks_)*2 + kk)) << 10)); \
    }while(0)

    #define LOADP(ks_) do{                                                             \
        w8 = (unsigned)(prowp[ks_] >> (pch*8)) & 0xffu;                                \
        int jb_ = (ks_)*64 + pch*8;                                                    \
        *(float4*)&fv[0] = *(const float4*)&FG[0][jb_];                                \
        *(float4*)&fv[4] = *(const float4*)&FG[0][jb_+4];                              \
        *(float4*)&gv[0] = *(const float4*)&FG[1][jb_];                                \
        *(float4*)&gv[4] = *(const float4*)&FG[1][jb_+4];                              \
    }while(0)

    #define WRITEP(pbase_) do{                                                         \
        float pf_[8];                                                                  \
        _Pragma("unroll")                                                              \
        for (int e = 0; e < 8; ++e){                                                   \
            float xv_ = f1v + fv[e];                                                   \
            float p_ = __builtin_amdgcn_exp2f(fmaxf(xv_, ALPHA*xv_) + gv[e]);          \
            pf_[e] = ((w8 >> e) & 1u) ? p_ : 0.f;                                      \
        }                                                                              \
        union { h16x2 h2[4]; f16x8 v8; } pu_;                                          \
        pu_.h2[0] = __builtin_amdgcn_cvt_pkrtz(pf_[0], pf_[1]);                        \
        pu_.h2[1] = __builtin_amdgcn_cvt_pkrtz(pf_[2], pf_[3]);                        \
        pu_.h2[2] = __builtin_amdgcn_cvt_pkrtz(pf_[4], pf_[5]);                        \
        pu_.h2[3] = __builtin_amdgcn_cvt_pkrtz(pf_[6], pf_[7]);                        \
        *(f16x8*)((pbase_) + pso) = pu_.v8;                                            \
    }while(0)

    #define MFMA_STEP(reg_, pbase_) do{                                                \
        f16x8 pa_[4][2];                                                               \
        _Pragma("unroll")                                                              \
        for (int m = 0; m < 4; ++m){                                                   \
            int row_ = m*16 + lr;                                                      \
            _Pragma("unroll")                                                          \
            for (int kk = 0; kk < 2; ++kk)                                             \
                pa_[m][kk] = *(const f16x8*)((pbase_) + row_*128 + (((kk*4 + lg) << 4) ^ ((row_ & 7) << 4))); \
        }                                                                              \
        _Pragma("unroll")                                                              \
        for (int n = 0; n < 2; ++n)                                                    \
          _Pragma("unroll")                                                            \
          for (int kk = 0; kk < 2; ++kk){                                              \
            f16x8 bf_ = *(const f16x8*)&reg_[n*2+kk];                                  \
            _Pragma("unroll")                                                          \
            for (int m = 0; m < 4; ++m)                                                \
                acc[m][n] = __builtin_amdgcn_mfma_f32_16x16x32_f16(pa_[m][kk], bf_, acc[m][n], 0, 0, 0); \
          }                                                                            \
    }while(0)

    LOADB(brega, 0);
    __syncthreads();
    LOADP(0); WRITEP(Ps0);
    __syncthreads();
    for (int ks2 = 0; ks2 < 16; ++ks2){
        int s = 2*ks2;
        LOADB(bregb, s+1); LOADP(s+1);
        MFMA_STEP(brega, Ps0);
        WRITEP(Ps1);
        __syncthreads();
        if (ks2 < 15){ LOADB(brega, s+2); LOADP(s+2); }
        MFMA_STEP(bregb, Ps1);
        if (ks2 < 15){ WRITEP(Ps0); __syncthreads(); }
    }
    #undef LOADB
    #undef LOADP
    #undef WRITEP
    #undef MFMA_STEP

    size_t obase = (size_t)b*NN*FF;
    #pragma unroll
    for (int m = 0; m < 4; ++m){
        #pragma unroll
        for (int q = 0; q < 4; ++q){
            size_t row = i0 + m*16 + lg*4 + q;
            #pragma unroll
            for (int n = 0; n < 2; ++n){
                int col = wid*32 + n*16 + lr;
                out[obase + row*FF + col] = lrelu(acc[m][n][q]);
            }
        }
    }
}

// ----------------------------------------------------------------
extern "C" void kernel_launch(void* const* d_in, const int* in_sizes, int n_in,
                              void* d_out, int out_size, void* d_ws, size_t ws_size,
                              hipStream_t stream){
    const float* x     = (const float*)d_in[0];
    const int*   adj   = (const int*)  d_in[1];
    const float* W0    = (const float*)d_in[2];
    const float* Wrest = (const float*)d_in[3];
    const float* A     = (const float*)d_in[4];
    float* out = (float*)d_out;

    char* ws = (char*)d_ws;
    size_t off = 0;
    auto carve = [&](size_t bytes) -> void* {
        void* p = ws + off;
        off += (bytes + 255) & ~(size_t)255;
        return p;
    };
    u64*      packed = (u64*)     carve((size_t)BB*NN*NN/8);
    _Float16* hA     = (_Float16*)carve((size_t)BB*NN*FF*2);
    char*     Bp0    = (char*)    carve((size_t)BB*NN*FF*2);
    char*     Bp1    = (char*)    carve((size_t)BB*NN*FF*2);
    _Float16* Wt     = (_Float16*)carve((size_t)4*FF*FF*2);
    float*    f1a    = (float*)   carve((size_t)BBNN*4);
    float*    f2a    = (float*)   carve((size_t)BBNN*4);
    float*    f1b    = (float*)   carve((size_t)BBNN*4);
    float*    f2b    = (float*)   carve((size_t)BBNN*4);
    float*    g      = (float*)   carve((size_t)BBNN*4);

    float* f1s[2] = {f1a, f1b};
    float* f2s[2] = {f2a, f2b};
    char*  Bps[2] = {Bp0, Bp1};

    pack_prep<<<2048, 256, 0, stream>>>(adj, packed, x, hA, W0, Wrest, Wt);
    gemm_hw<<<256, 512, 0, stream>>>(hA, Wt, A, Bp0, f1a, f2a);
    for (int lyr = 0; lyr < 3; ++lyr){
        spass_g<<<512, 512, 0, stream>>>(packed, f1s[lyr & 1], f2s[lyr & 1], g);
        att_hw<<<256, 512, 0, stream>>>(Bps[lyr & 1], Bps[(lyr + 1) & 1], packed,
                                        f1s[lyr & 1], f2s[lyr & 1], g,
                                        Wt + (size_t)(lyr + 1)*FF*FF, A + (size_t)(lyr + 1)*2*FF,
                                        f1s[(lyr + 1) & 1], f2s[(lyr + 1) & 1]);
    }
    spass_g<<<512, 512, 0, stream>>>(packed, f1s[1], f2s[1], g);
    att_last<<<256, 512, 0, stream>>>(Bps[1], packed, f1s[1], f2s[1], g, out);
}